// Round 4
// baseline (389.180 us; speedup 1.0000x reference)
//
#include <hip/hip_runtime.h>

typedef unsigned short u16;
typedef unsigned int u32;
typedef __attribute__((ext_vector_type(4))) float f32x4;
typedef __attribute__((ext_vector_type(8))) short s16x8;
typedef __attribute__((ext_vector_type(4))) u16 u16x4;

#define L2E 1.4426950408889634f
#define QSCALE 0.18033688011112042f /* (1/8) * log2(e) */

__device__ __forceinline__ u16 f2bf(float f) {  // RNE
    union { float f; u32 i; } v; v.f = f;
    return (u16)((v.i + 0x7fffu + ((v.i >> 16) & 1u)) >> 16);
}
__device__ __forceinline__ u16 f2bf_rn(float f) {
    union { float f; u32 i; } v; v.f = f;
    return (u16)((v.i + 0x8000u) >> 16);
}

// async global->LDS, 16B per lane; lds dest must be wave-uniform base (+lane*16)
__device__ __forceinline__ void gl2lds16(const u16* g, u16* l) {
    __builtin_amdgcn_global_load_lds(
        (const __attribute__((address_space(1))) void*)g,
        (__attribute__((address_space(3))) void*)l, 16, 0, 0);
}

// ---------------------------------------------------------------------------
// Convert the 6 big fp32 tensors (Qin, KVin, Wq, Wk, Wv, Wo) to bf16 in ws.
// ---------------------------------------------------------------------------
__global__ __launch_bounds__(256) void conv_kernel(
    const float* __restrict__ s0, const float* __restrict__ s1,
    const float* __restrict__ s2, const float* __restrict__ s3,
    const float* __restrict__ s4, const float* __restrict__ s5,
    u16* __restrict__ dst)
{
    int e = (blockIdx.x * 256 + threadIdx.x) * 4;
    const float* src; int off;
    if      (e < 4194304) { src = s0; off = e; }
    else if (e < 8388608) { src = s1; off = e - 4194304; }
    else if (e < 8650752) { src = s2; off = e - 8388608; }
    else if (e < 8912896) { src = s3; off = e - 8650752; }
    else if (e < 9175040) { src = s4; off = e - 8912896; }
    else                  { src = s5; off = e - 9175040; }
    f32x4 f = *(const f32x4*)(src + off);
    u16x4 o;
#pragma unroll
    for (int j = 0; j < 4; ++j) o[j] = f2bf(f[j]);
    *(u16x4*)(dst + e) = o;
}

// ---------------------------------------------------------------------------
// GEMM core (m97 structure): C[128x128] = A[128x512] * B^T, bf16.
// global_load_lds width-16 staging into UNPADDED As/Bs[128][32].
// Staging map: wave w, call j, lane l -> LDS u16 off w*1024+j*512+l*8,
// which equals row-major (row=w*32+j*16+l/4)*32 + (l&3)*8 exactly.
// ---------------------------------------------------------------------------
__device__ __forceinline__ void gemm_core(
    const u16* __restrict__ A, const u16* __restrict__ Bw,
    int m0, int n0, u16* As, u16* Bs, f32x4 acc[4][4])
{
    const int tid = threadIdx.x;
    const int lane = tid & 63, w = tid >> 6;
    const int wm = w >> 1, wn = w & 1;
    const int l16 = lane & 15, quad = lane >> 4;
    const int srow = (lane >> 2), sch = (lane & 3) * 8;
    const f32x4 vzero = {0.f, 0.f, 0.f, 0.f};
#pragma unroll
    for (int i = 0; i < 4; ++i)
#pragma unroll
        for (int j = 0; j < 4; ++j) acc[i][j] = vzero;

    for (int kt = 0; kt < 16; ++kt) {
#pragma unroll
        for (int j = 0; j < 2; ++j) {
            int row = w * 32 + j * 16 + srow;
            gl2lds16(&A[(size_t)(m0 + row) * 512 + kt * 32 + sch],
                     &As[w * 1024 + j * 512]);
            gl2lds16(&Bw[(size_t)(n0 + row) * 512 + kt * 32 + sch],
                     &Bs[w * 1024 + j * 512]);
        }
        __syncthreads();
        s16x8 af[4], bfr[4];
#pragma unroll
        for (int mt = 0; mt < 4; ++mt)
            af[mt] = *(const s16x8*)&As[(wm * 64 + mt * 16 + l16) * 32 + quad * 8];
#pragma unroll
        for (int nt = 0; nt < 4; ++nt)
            bfr[nt] = *(const s16x8*)&Bs[(wn * 64 + nt * 16 + l16) * 32 + quad * 8];
#pragma unroll
        for (int mt = 0; mt < 4; ++mt)
#pragma unroll
            for (int nt = 0; nt < 4; ++nt)
                acc[mt][nt] = __builtin_amdgcn_mfma_f32_16x16x32_bf16(
                    af[mt], bfr[nt], acc[mt][nt], 0, 0, 0);
        __syncthreads();
    }
}

// ---------------------------------------------------------------------------
// QKV projection. job 0=Q (scaled, ->[B,H,N,64]), 1=K, 2=V (-> [B,H,64,N]).
// ---------------------------------------------------------------------------
__global__ __launch_bounds__(256) void proj_kernel(
    const u16* __restrict__ cQin, const u16* __restrict__ cKV,
    const u16* __restrict__ cW,
    const float* __restrict__ bq, const float* __restrict__ bk,
    const float* __restrict__ bv,
    u16* __restrict__ Qh, u16* __restrict__ Kh, u16* __restrict__ Vt)
{
    __shared__ __align__(16) u16 As[128 * 32];
    __shared__ __align__(16) u16 Bs[128 * 32];
    const int job = blockIdx.z;
    const u16* A = (job == 0) ? cQin : cKV;
    const u16* W = cW + (size_t)job * 262144;
    const float* bias = (job == 0) ? bq : (job == 1 ? bk : bv);
    const int m0 = blockIdx.y * 128, n0 = blockIdx.x * 128;
    f32x4 acc[4][4];
    gemm_core(A, W, m0, n0, As, Bs, acc);

    const int tid = threadIdx.x, lane = tid & 63, w = tid >> 6;
    const int wm = w >> 1, wn = w & 1, l16 = lane & 15, quad = lane >> 4;
#pragma unroll
    for (int nt = 0; nt < 4; ++nt) {
        int j = n0 + wn * 64 + nt * 16 + l16;
        float bj = bias[j];
        int h = j >> 6, d = j & 63;
#pragma unroll
        for (int mt = 0; mt < 4; ++mt) {
            int trow = m0 + wm * 64 + mt * 16 + quad * 4;
            int bb = trow >> 11, nn = trow & 2047;
            int bh = bb * 8 + h;
            if (job == 2) {
                u16x4 pv;
#pragma unroll
                for (int reg = 0; reg < 4; ++reg) pv[reg] = f2bf(acc[mt][nt][reg] + bj);
                *(u16x4*)&Vt[(size_t)(bh * 64 + d) * 2048 + nn] = pv;
            } else if (job == 0) {
#pragma unroll
                for (int reg = 0; reg < 4; ++reg)
                    Qh[(size_t)(bh * 2048 + nn + reg) * 64 + d] =
                        f2bf((acc[mt][nt][reg] + bj) * QSCALE);
            } else {
#pragma unroll
                for (int reg = 0; reg < 4; ++reg)
                    Kh[(size_t)(bh * 2048 + nn + reg) * 64 + d] =
                        f2bf(acc[mt][nt][reg] + bj);
            }
        }
    }
}

// ---------------------------------------------------------------------------
// Attention, barrier-free. Grid (32 q64-tiles, 2 head-groups, 4 batches),
// block 512 = 8 waves; wave = (head = hg*4 + w>>1, q0 = qt*64 + (w&1)*32).
// S^T = K·Q^T so q lands in lane&15: gate SC values are per-lane f32x4 loads,
// computed inline (sigmoid+eps, exp2) — no shared state, no __syncthreads.
// P round-trips through wave-private padded LDS (writes 8B vec, 4-way max).
// ---------------------------------------------------------------------------
__global__ __launch_bounds__(512) void attn_kernel(
    const u16* __restrict__ Qh, const u16* __restrict__ Kh,
    const u16* __restrict__ Vt, const float* __restrict__ SC,
    const float* __restrict__ gwp, const float* __restrict__ gbp,
    u16* __restrict__ Ob)
{
    __shared__ __align__(16) u16 Plds[8][32][68];
    const int tid = threadIdx.x;
    const int w = tid >> 6, lane = tid & 63;
    const int l16 = lane & 15, quad = lane >> 4;
    const int b = blockIdx.z;
    const int head = blockIdx.y * 4 + (w >> 1);
    const int q0 = blockIdx.x * 64 + (w & 1) * 32;
    const int bh = b * 8 + head;
    const float gw = gwp[0], gb = gbp[0];
    const float tA = -gw * L2E, tB = -gb * L2E;  // t = tA*sc + tB = -u*log2e
    const u16* Qp = Qh + (size_t)bh * 131072;
    const u16* Kp = Kh + (size_t)bh * 131072;
    const u16* Vp = Vt + (size_t)bh * 131072;
    const float* SCp = SC + (size_t)b * 4194304;
    const f32x4 vzero = {0.f, 0.f, 0.f, 0.f};

    s16x8 qf[2][2];  // B-operand: Q[n=q=l16][k=d=quad*8+j]
#pragma unroll
    for (int qt = 0; qt < 2; ++qt)
#pragma unroll
        for (int kc = 0; kc < 2; ++kc)
            qf[qt][kc] = *(const s16x8*)&Qp[(size_t)(q0 + qt * 16 + l16) * 64 +
                                            kc * 32 + quad * 8];
    f32x4 o[2][4];
    float lsum[2] = {0.f, 0.f};
#pragma unroll
    for (int qt = 0; qt < 2; ++qt)
#pragma unroll
        for (int dn = 0; dn < 4; ++dn) o[qt][dn] = vzero;

    for (int kt = 0; kt < 32; ++kt) {
        const int k0 = kt * 64;
        // SC gate inputs, per-lane vectorized (issued early to overlap MFMA)
        f32x4 sc4[4][2];
#pragma unroll
        for (int kk = 0; kk < 4; ++kk)
#pragma unroll
            for (int qt = 0; qt < 2; ++qt)
                sc4[kk][qt] = *(const f32x4*)&SCp[(size_t)(q0 + qt * 16 + l16) * 2048 +
                                                  k0 + kk * 16 + quad * 4];
        s16x8 kf[4][2];  // A-operand: K[m=key=l16][k=d=quad*8+j]
#pragma unroll
        for (int kk = 0; kk < 4; ++kk)
#pragma unroll
            for (int kc = 0; kc < 2; ++kc)
                kf[kk][kc] = *(const s16x8*)&Kp[(size_t)(k0 + kk * 16 + l16) * 64 +
                                                kc * 32 + quad * 8];
        s16x8 vf[4][2];  // B-operand: V[n=d=l16][k=key=quad*8+j] from Vt
#pragma unroll
        for (int dn = 0; dn < 4; ++dn)
#pragma unroll
            for (int kc = 0; kc < 2; ++kc)
                vf[dn][kc] = *(const s16x8*)&Vp[(size_t)(dn * 16 + l16) * 2048 +
                                                k0 + kc * 32 + quad * 8];
        // S^T tiles [key][q]: row=key=quad*4+reg, col=q=l16
        f32x4 st[4][2];
#pragma unroll
        for (int kk = 0; kk < 4; ++kk)
#pragma unroll
            for (int qt = 0; qt < 2; ++qt) {
                f32x4 z = vzero;
                z = __builtin_amdgcn_mfma_f32_16x16x32_bf16(kf[kk][0], qf[qt][0], z, 0, 0, 0);
                st[kk][qt] = __builtin_amdgcn_mfma_f32_16x16x32_bf16(kf[kk][1], qf[qt][1], z, 0, 0, 0);
            }
        // gate + P: p = 2^st * (sigmoid(u)+1e-8); write u16x4 to wave-private LDS
#pragma unroll
        for (int kk = 0; kk < 4; ++kk)
#pragma unroll
            for (int qt = 0; qt < 2; ++qt) {
                u16x4 pp;
#pragma unroll
                for (int reg = 0; reg < 4; ++reg) {
                    float t = tA * sc4[kk][qt][reg] + tB;
                    float g = __builtin_amdgcn_rcpf(1.0f + __builtin_amdgcn_exp2f(t)) + 1e-8f;
                    float p = __builtin_amdgcn_exp2f(st[kk][qt][reg]) * g;
                    lsum[qt] += p;
                    pp[reg] = f2bf_rn(p);
                }
                *(u16x4*)&Plds[w][qt * 16 + l16][kk * 16 + quad * 4] = pp;
            }
        // PV: A-operand P[m=q=l16][k=key=quad*8+j]
#pragma unroll
        for (int qt = 0; qt < 2; ++qt)
#pragma unroll
            for (int kc = 0; kc < 2; ++kc) {
                s16x8 pf = *(const s16x8*)&Plds[w][qt * 16 + l16][kc * 32 + quad * 8];
#pragma unroll
                for (int dn = 0; dn < 4; ++dn)
                    o[qt][dn] = __builtin_amdgcn_mfma_f32_16x16x32_bf16(
                        pf, vf[dn][kc], o[qt][dn], 0, 0, 0);
            }
    }
    // lsum held per-lane for q-row l16 (partial over quads): reduce, redistribute
#pragma unroll
    for (int qt = 0; qt < 2; ++qt) {
        float l = lsum[qt];
        l += __shfl_xor(l, 16, 64);
        l += __shfl_xor(l, 32, 64);
        float inv = __builtin_amdgcn_rcpf(l);
#pragma unroll
        for (int reg = 0; reg < 4; ++reg) {
            float invr = __shfl(inv, quad * 4 + reg, 64);  // holder lane l16==quad*4+reg
            int trow = b * 2048 + q0 + qt * 16 + quad * 4 + reg;
#pragma unroll
            for (int dn = 0; dn < 4; ++dn)
                Ob[(size_t)trow * 512 + head * 64 + dn * 16 + l16] =
                    f2bf(o[qt][dn][reg] * invr);
        }
    }
}

// ---------------------------------------------------------------------------
// Output projection: out = Ob @ Wo^T + bo, fp32 out.
// ---------------------------------------------------------------------------
__global__ __launch_bounds__(256) void out_kernel(
    const u16* __restrict__ Ob, const u16* __restrict__ cWo,
    const float* __restrict__ bo, float* __restrict__ out)
{
    __shared__ __align__(16) u16 As[128 * 32];
    __shared__ __align__(16) u16 Bs[128 * 32];
    const int m0 = blockIdx.y * 128, n0 = blockIdx.x * 128;
    f32x4 acc[4][4];
    gemm_core(Ob, cWo, m0, n0, As, Bs, acc);
    const int tid = threadIdx.x, lane = tid & 63, w = tid >> 6;
    const int wm = w >> 1, wn = w & 1, l16 = lane & 15, quad = lane >> 4;
#pragma unroll
    for (int nt = 0; nt < 4; ++nt) {
        int j = n0 + wn * 64 + nt * 16 + l16;
        float bj = bo[j];
#pragma unroll
        for (int mt = 0; mt < 4; ++mt) {
            int t = m0 + wm * 64 + mt * 16 + quad * 4;
#pragma unroll
            for (int reg = 0; reg < 4; ++reg)
                out[(size_t)(t + reg) * 512 + j] = acc[mt][nt][reg] + bj;
        }
    }
}

extern "C" void kernel_launch(void* const* d_in, const int* in_sizes, int n_in,
                              void* d_out, int out_size, void* d_ws, size_t ws_size,
                              hipStream_t stream)
{
    const float* Qin  = (const float*)d_in[0];
    const float* KVin = (const float*)d_in[1];
    const float* SC   = (const float*)d_in[2];
    const float* Wq   = (const float*)d_in[3];
    const float* bq   = (const float*)d_in[4];
    const float* Wk   = (const float*)d_in[5];
    const float* bk   = (const float*)d_in[6];
    const float* Wv   = (const float*)d_in[7];
    const float* bv   = (const float*)d_in[8];
    const float* gw   = (const float*)d_in[9];
    const float* gb   = (const float*)d_in[10];
    const float* Wo   = (const float*)d_in[11];
    const float* bo   = (const float*)d_in[12];
    float* out = (float*)d_out;

    // ws layout (u16 units), 52.4 MB total (same footprint as passing R3)
    u16* conv = (u16*)d_ws;            // 9,437,184: cQin|cKV|cWq|cWk|cWv|cWo
    u16* cQin = conv;
    u16* cKV  = conv + 4194304;
    u16* cW   = conv + 8388608;        // Wq,Wk,Wv,Wo each 262,144
    u16* Qh   = conv + 9437184;        // each 4,194,304
    u16* Kh   = Qh + 4194304;
    u16* Vt   = Kh + 4194304;
    u16* Ob   = Vt + 4194304;

    hipLaunchKernelGGL(conv_kernel, dim3(9216), dim3(256), 0, stream,
                       Qin, KVin, Wq, Wk, Wv, Wo, conv);
    hipLaunchKernelGGL(proj_kernel, dim3(4, 64, 3), dim3(256), 0, stream,
                       cQin, cKV, cW, bq, bk, bv, Qh, Kh, Vt);
    hipLaunchKernelGGL(attn_kernel, dim3(32, 2, 4), dim3(512), 0, stream,
                       Qh, Kh, Vt, SC, gw, gb, Ob);
    hipLaunchKernelGGL(out_kernel, dim3(4, 64), dim3(256), 0, stream,
                       Ob, cW + 786432, bo, out);
}

// Round 5
// 283.793 us; speedup vs baseline: 1.3714x; 1.3714x over previous
//
#include <hip/hip_runtime.h>

typedef unsigned short u16;
typedef unsigned int u32;
typedef __attribute__((ext_vector_type(4))) float f32x4;
typedef __attribute__((ext_vector_type(8))) short s16x8;
typedef __attribute__((ext_vector_type(4))) u16 u16x4;

#define L2E 1.4426950408889634f
#define QSCALE 0.18033688011112042f /* (1/8) * log2(e) */

__device__ __forceinline__ float bf2f(u16 u) {
    union { u32 i; float f; } v; v.i = ((u32)u) << 16; return v.f;
}
__device__ __forceinline__ u16 f2bf(float f) {  // RNE
    union { float f; u32 i; } v; v.f = f;
    return (u16)((v.i + 0x7fffu + ((v.i >> 16) & 1u)) >> 16);
}
__device__ __forceinline__ u16 f2bf_rn(float f) {
    union { float f; u32 i; } v; v.f = f;
    return (u16)((v.i + 0x8000u) >> 16);
}

// async global->LDS, 16B per lane; LDS dest = wave-uniform base + lane*16
__device__ __forceinline__ void gl2lds16(const u16* g, u16* l) {
    __builtin_amdgcn_global_load_lds(
        (const __attribute__((address_space(1))) void*)g,
        (__attribute__((address_space(3))) void*)l, 16, 0, 0);
}

// ---------------------------------------------------------------------------
// Convert the 6 big fp32 tensors (Qin, KVin, Wq, Wk, Wv, Wo) to bf16 in ws.
// ---------------------------------------------------------------------------
__global__ __launch_bounds__(256) void conv_kernel(
    const float* __restrict__ s0, const float* __restrict__ s1,
    const float* __restrict__ s2, const float* __restrict__ s3,
    const float* __restrict__ s4, const float* __restrict__ s5,
    u16* __restrict__ dst)
{
    int e = (blockIdx.x * 256 + threadIdx.x) * 4;
    const float* src; int off;
    if      (e < 4194304) { src = s0; off = e; }
    else if (e < 8388608) { src = s1; off = e - 4194304; }
    else if (e < 8650752) { src = s2; off = e - 8388608; }
    else if (e < 8912896) { src = s3; off = e - 8650752; }
    else if (e < 9175040) { src = s4; off = e - 8912896; }
    else                  { src = s5; off = e - 9175040; }
    f32x4 f = *(const f32x4*)(src + off);
    u16x4 o;
#pragma unroll
    for (int j = 0; j < 4; ++j) o[j] = f2bf(f[j]);
    *(u16x4*)(dst + e) = o;
}

// ---------------------------------------------------------------------------
// LG[b][q][k] = log2(sigmoid(gw*SC+gb) + 1e-8), bf16 — gate computed ONCE.
// ---------------------------------------------------------------------------
__global__ __launch_bounds__(256) void lg_kernel(
    const float* __restrict__ SC, const float* __restrict__ gwp,
    const float* __restrict__ gbp, u16* __restrict__ LG)
{
    int i = (blockIdx.x * 256 + threadIdx.x) * 4;
    const float tA = -gwp[0] * L2E, tB = -gbp[0] * L2E;
    f32x4 x = *(const f32x4*)(SC + i);
    u16x4 o;
#pragma unroll
    for (int j = 0; j < 4; ++j) {
        float g = __builtin_amdgcn_rcpf(
                      1.0f + __builtin_amdgcn_exp2f(tA * x[j] + tB)) + 1e-8f;
        o[j] = f2bf(__builtin_amdgcn_logf(g));  // v_log_f32 = log2
    }
    *(u16x4*)(LG + i) = o;
}

// ---------------------------------------------------------------------------
// GEMM core (m97 structure): C[128x128] = A[128x512] * B^T, bf16.
// ---------------------------------------------------------------------------
__device__ __forceinline__ void gemm_core(
    const u16* __restrict__ A, const u16* __restrict__ Bw,
    int m0, int n0, u16* As, u16* Bs, f32x4 acc[4][4])
{
    const int tid = threadIdx.x;
    const int lane = tid & 63, w = tid >> 6;
    const int wm = w >> 1, wn = w & 1;
    const int l16 = lane & 15, quad = lane >> 4;
    const int srow = (lane >> 2), sch = (lane & 3) * 8;
    const f32x4 vzero = {0.f, 0.f, 0.f, 0.f};
#pragma unroll
    for (int i = 0; i < 4; ++i)
#pragma unroll
        for (int j = 0; j < 4; ++j) acc[i][j] = vzero;

    for (int kt = 0; kt < 16; ++kt) {
#pragma unroll
        for (int j = 0; j < 2; ++j) {
            int row = w * 32 + j * 16 + srow;
            gl2lds16(&A[(size_t)(m0 + row) * 512 + kt * 32 + sch],
                     &As[w * 1024 + j * 512]);
            gl2lds16(&Bw[(size_t)(n0 + row) * 512 + kt * 32 + sch],
                     &Bs[w * 1024 + j * 512]);
        }
        __syncthreads();
        s16x8 af[4], bfr[4];
#pragma unroll
        for (int mt = 0; mt < 4; ++mt)
            af[mt] = *(const s16x8*)&As[(wm * 64 + mt * 16 + l16) * 32 + quad * 8];
#pragma unroll
        for (int nt = 0; nt < 4; ++nt)
            bfr[nt] = *(const s16x8*)&Bs[(wn * 64 + nt * 16 + l16) * 32 + quad * 8];
#pragma unroll
        for (int mt = 0; mt < 4; ++mt)
#pragma unroll
            for (int nt = 0; nt < 4; ++nt)
                acc[mt][nt] = __builtin_amdgcn_mfma_f32_16x16x32_bf16(
                    af[mt], bfr[nt], acc[mt][nt], 0, 0, 0);
        __syncthreads();
    }
}

// ---------------------------------------------------------------------------
// QKV projection. job 0=Q (scaled, ->[B,H,N,64]), 1=K, 2=V (-> [B,H,64,N]).
// ---------------------------------------------------------------------------
__global__ __launch_bounds__(256) void proj_kernel(
    const u16* __restrict__ cQin, const u16* __restrict__ cKV,
    const u16* __restrict__ cW,
    const float* __restrict__ bq, const float* __restrict__ bk,
    const float* __restrict__ bv,
    u16* __restrict__ Qh, u16* __restrict__ Kh, u16* __restrict__ Vt)
{
    __shared__ __align__(16) u16 As[128 * 32];
    __shared__ __align__(16) u16 Bs[128 * 32];
    const int job = blockIdx.z;
    const u16* A = (job == 0) ? cQin : cKV;
    const u16* W = cW + (size_t)job * 262144;
    const float* bias = (job == 0) ? bq : (job == 1 ? bk : bv);
    const int m0 = blockIdx.y * 128, n0 = blockIdx.x * 128;
    f32x4 acc[4][4];
    gemm_core(A, W, m0, n0, As, Bs, acc);

    const int tid = threadIdx.x, lane = tid & 63, w = tid >> 6;
    const int wm = w >> 1, wn = w & 1, l16 = lane & 15, quad = lane >> 4;
#pragma unroll
    for (int nt = 0; nt < 4; ++nt) {
        int j = n0 + wn * 64 + nt * 16 + l16;
        float bj = bias[j];
        int h = j >> 6, d = j & 63;
#pragma unroll
        for (int mt = 0; mt < 4; ++mt) {
            int trow = m0 + wm * 64 + mt * 16 + quad * 4;
            int bb = trow >> 11, nn = trow & 2047;
            int bh = bb * 8 + h;
            if (job == 2) {
                u16x4 pv;
#pragma unroll
                for (int reg = 0; reg < 4; ++reg) pv[reg] = f2bf(acc[mt][nt][reg] + bj);
                *(u16x4*)&Vt[(size_t)(bh * 64 + d) * 2048 + nn] = pv;
            } else if (job == 0) {
#pragma unroll
                for (int reg = 0; reg < 4; ++reg)
                    Qh[(size_t)(bh * 2048 + nn + reg) * 64 + d] =
                        f2bf((acc[mt][nt][reg] + bj) * QSCALE);
            } else {
#pragma unroll
                for (int reg = 0; reg < 4; ++reg)
                    Kh[(size_t)(bh * 2048 + nn + reg) * 64 + d] =
                        f2bf(acc[mt][nt][reg] + bj);
            }
        }
    }
}

// ---------------------------------------------------------------------------
// Attention. Block = 1024 thr = 16 waves = (1 head, 256 q-rows); wave = 16 q.
// Grid (8 qg, 8 head, 4 b) = 256 blocks, 16 waves/CU. K/V tiles (64keys x 64d)
// double-buffered in LDS via global_load_lds, shared by all 16 waves; one
// barrier per k-iter, next-tile loads issued right after it. XOR-swizzled
// chunk placement keeps ds_read_b128 at <=2-way conflicts. Gate via LG (bf16).
// ---------------------------------------------------------------------------
__global__ __launch_bounds__(1024, 4) void attn_kernel(
    const u16* __restrict__ Qh, const u16* __restrict__ Kh,
    const u16* __restrict__ Vt, const u16* __restrict__ LG,
    u16* __restrict__ Ob)
{
    __shared__ __align__(16) u16 Ks[2][4096];      // [buf][key][d]  (swizzled)
    __shared__ __align__(16) u16 Vs[2][4096];      // [buf][d][key]  (swizzled)
    __shared__ __align__(16) u16 Plds[16][16][68]; // per-wave P
    const int tid = threadIdx.x;
    const int w = tid >> 6, lane = tid & 63;
    const int l16 = lane & 15, quad = lane >> 4;
    const int b = blockIdx.z, head = blockIdx.y;
    const int bh = b * 8 + head;
    const int q0 = blockIdx.x * 256 + w * 16;
    const u16* Qp = Qh + (size_t)bh * 131072;
    const u16* Kp = Kh + (size_t)bh * 131072;
    const u16* Vp = Vt + (size_t)bh * 131072;
    const u16* LGp = LG + (size_t)b * 4194304 + (size_t)(q0 + l16) * 2048;
    const f32x4 vzero = {0.f, 0.f, 0.f, 0.f};

    // staging assignment: waves 0-7 stage K rows, waves 8-15 stage V rows
    const int sr = lane >> 3;                       // row within 8-row slab
    const int sc = ((lane & 7) ^ (sr & 7)) * 8;     // swizzled 8-u16 chunk
    const int slab = (w & 7) * 8;
    const u16* sK = Kp + (size_t)(slab + sr) * 64 + sc;    // advance 4096/iter
    const u16* sV = Vp + (size_t)(slab + sr) * 2048 + sc;  // advance 64/iter

    s16x8 qf[2];  // B-operand: Q[n=q=l16][k=d=kc*32+quad*8+j]
#pragma unroll
    for (int kc = 0; kc < 2; ++kc)
        qf[kc] = *(const s16x8*)&Qp[(size_t)(q0 + l16) * 64 + kc * 32 + quad * 8];
    f32x4 o[4];
    float lsum = 0.f;
#pragma unroll
    for (int dn = 0; dn < 4; ++dn) o[dn] = vzero;

    // prologue: stage buf 0 (k-tile 0)
    if (w < 8) gl2lds16(sK, &Ks[0][slab * 64]);
    else       gl2lds16(sV, &Vs[0][slab * 64]);

    for (int kt = 0; kt < 32; ++kt) {
        __syncthreads();  // drains this wave's staging load; tile[cur] ready
        const int cur = kt & 1;
        if (kt < 31) {    // async-stage next tile into the other buffer
            if (w < 8) gl2lds16(sK + (size_t)(kt + 1) * 4096, &Ks[cur ^ 1][slab * 64]);
            else       gl2lds16(sV + (size_t)(kt + 1) * 64,   &Vs[cur ^ 1][slab * 64]);
        }
        const u16* Kb = Ks[cur];
        const u16* Vb = Vs[cur];
        const int k0 = kt * 64;

        // S^T[key][q] = K·Q^T : A=K-tile rows, B=q fragment
        f32x4 st[4];
#pragma unroll
        for (int kc = 0; kc < 2; ++kc) {
            s16x8 kf[4];
#pragma unroll
            for (int kk = 0; kk < 4; ++kk)
                kf[kk] = *(const s16x8*)&Kb[(kk * 16 + l16) * 64 +
                                            ((kc * 4 + quad) ^ (l16 & 7)) * 8];
#pragma unroll
            for (int kk = 0; kk < 4; ++kk)
                st[kk] = __builtin_amdgcn_mfma_f32_16x16x32_bf16(
                    kf[kk], qf[kc], kc == 0 ? vzero : st[kk], 0, 0, 0);
        }
        // P = 2^(S*log2e + LG); row sums; stash bf16 P in wave-private LDS
#pragma unroll
        for (int kk = 0; kk < 4; ++kk) {
            u16x4 lg4 = *(const u16x4*)&LGp[k0 + kk * 16 + quad * 4];
            u16x4 pp;
#pragma unroll
            for (int reg = 0; reg < 4; ++reg) {
                float p = __builtin_amdgcn_exp2f(st[kk][reg] + bf2f(lg4[reg]));
                lsum += p;
                pp[reg] = f2bf_rn(p);
            }
            *(u16x4*)&Plds[w][l16][kk * 16 + quad * 4] = pp;
        }
        // PV: A = P[m=q][k=key], B = V[n=d][k=key]
#pragma unroll
        for (int kc = 0; kc < 2; ++kc) {
            s16x8 pf = *(const s16x8*)&Plds[w][l16][kc * 32 + quad * 8];
            s16x8 vf[4];
#pragma unroll
            for (int dn = 0; dn < 4; ++dn)
                vf[dn] = *(const s16x8*)&Vb[(dn * 16 + l16) * 64 +
                                            ((kc * 4 + quad) ^ (l16 & 7)) * 8];
#pragma unroll
            for (int dn = 0; dn < 4; ++dn)
                o[dn] = __builtin_amdgcn_mfma_f32_16x16x32_bf16(
                    pf, vf[dn], o[dn], 0, 0, 0);
        }
    }
    // lsum per lane holds q=l16 (partial over quads): reduce, redistribute
    lsum += __shfl_xor(lsum, 16, 64);
    lsum += __shfl_xor(lsum, 32, 64);
    float inv = __builtin_amdgcn_rcpf(lsum);
#pragma unroll
    for (int reg = 0; reg < 4; ++reg) {
        float invr = __shfl(inv, quad * 4 + reg, 64);  // from lane with l16==q
        int trow = b * 2048 + q0 + quad * 4 + reg;
#pragma unroll
        for (int dn = 0; dn < 4; ++dn)
            Ob[(size_t)trow * 512 + head * 64 + dn * 16 + l16] =
                f2bf(o[dn][reg] * invr);
    }
}

// ---------------------------------------------------------------------------
// Output projection: out = Ob @ Wo^T + bo, fp32 out.
// ---------------------------------------------------------------------------
__global__ __launch_bounds__(256) void out_kernel(
    const u16* __restrict__ Ob, const u16* __restrict__ cWo,
    const float* __restrict__ bo, float* __restrict__ out)
{
    __shared__ __align__(16) u16 As[128 * 32];
    __shared__ __align__(16) u16 Bs[128 * 32];
    const int m0 = blockIdx.y * 128, n0 = blockIdx.x * 128;
    f32x4 acc[4][4];
    gemm_core(Ob, cWo, m0, n0, As, Bs, acc);
    const int tid = threadIdx.x, lane = tid & 63, w = tid >> 6;
    const int wm = w >> 1, wn = w & 1, l16 = lane & 15, quad = lane >> 4;
#pragma unroll
    for (int nt = 0; nt < 4; ++nt) {
        int j = n0 + wn * 64 + nt * 16 + l16;
        float bj = bo[j];
#pragma unroll
        for (int mt = 0; mt < 4; ++mt) {
            int t = m0 + wm * 64 + mt * 16 + quad * 4;
#pragma unroll
            for (int reg = 0; reg < 4; ++reg)
                out[(size_t)(t + reg) * 512 + j] = acc[mt][nt][reg] + bj;
        }
    }
}

extern "C" void kernel_launch(void* const* d_in, const int* in_sizes, int n_in,
                              void* d_out, int out_size, void* d_ws, size_t ws_size,
                              hipStream_t stream)
{
    const float* Qin  = (const float*)d_in[0];
    const float* KVin = (const float*)d_in[1];
    const float* SC   = (const float*)d_in[2];
    const float* Wq   = (const float*)d_in[3];
    const float* bq   = (const float*)d_in[4];
    const float* Wk   = (const float*)d_in[5];
    const float* bk   = (const float*)d_in[6];
    const float* Wv   = (const float*)d_in[7];
    const float* bv   = (const float*)d_in[8];
    const float* gw   = (const float*)d_in[9];
    const float* gb   = (const float*)d_in[10];
    const float* Wo   = (const float*)d_in[11];
    const float* bo   = (const float*)d_in[12];
    float* out = (float*)d_out;

    // ws layout (u16 units): conv 9.4M | Qh/Kh/Vt/Ob 4.2M each | LG 16.8M
    u16* conv = (u16*)d_ws;
    u16* cQin = conv;
    u16* cKV  = conv + 4194304;
    u16* cW   = conv + 8388608;        // Wq,Wk,Wv,Wo each 262,144
    u16* Qh   = conv + 9437184;
    u16* Kh   = Qh + 4194304;
    u16* Vt   = Kh + 4194304;
    u16* Ob   = Vt + 4194304;
    u16* LG   = Ob + 4194304;          // 16,777,216 u16 = 32 MiB

    hipLaunchKernelGGL(conv_kernel, dim3(9216), dim3(256), 0, stream,
                       Qin, KVin, Wq, Wk, Wv, Wo, conv);
    hipLaunchKernelGGL(lg_kernel, dim3(16384), dim3(256), 0, stream,
                       SC, gw, gb, LG);
    hipLaunchKernelGGL(proj_kernel, dim3(4, 64, 3), dim3(256), 0, stream,
                       cQin, cKV, cW, bq, bk, bv, Qh, Kh, Vt);
    hipLaunchKernelGGL(attn_kernel, dim3(8, 8, 4), dim3(1024), 0, stream,
                       Qh, Kh, Vt, LG, Ob);
    hipLaunchKernelGGL(out_kernel, dim3(4, 64), dim3(256), 0, stream,
                       Ob, cW + 786432, bo, out);
}

// Round 6
// 261.857 us; speedup vs baseline: 1.4862x; 1.0838x over previous
//
#include <hip/hip_runtime.h>

typedef unsigned short u16;
typedef unsigned int u32;
typedef __attribute__((ext_vector_type(4))) float f32x4;
typedef __attribute__((ext_vector_type(8))) short s16x8;
typedef __attribute__((ext_vector_type(4))) u16 u16x4;

#define L2E 1.4426950408889634f
#define QSCALE 0.18033688011112042f /* (1/8) * log2(e) */

__device__ __forceinline__ float bf2f(u16 u) {
    union { u32 i; float f; } v; v.i = ((u32)u) << 16; return v.f;
}
__device__ __forceinline__ u16 f2bf(float f) {  // RNE
    union { float f; u32 i; } v; v.f = f;
    return (u16)((v.i + 0x7fffu + ((v.i >> 16) & 1u)) >> 16);
}
__device__ __forceinline__ u16 f2bf_rn(float f) {
    union { float f; u32 i; } v; v.f = f;
    return (u16)((v.i + 0x8000u) >> 16);
}

// async global->LDS, 16B per lane; LDS dest = wave-uniform base + lane*16
__device__ __forceinline__ void gl2lds16(const u16* g, u16* l) {
    __builtin_amdgcn_global_load_lds(
        (const __attribute__((address_space(1))) void*)g,
        (__attribute__((address_space(3))) void*)l, 16, 0, 0);
}

// ---------------------------------------------------------------------------
// Convert the 6 big fp32 tensors (Qin, KVin, Wq, Wk, Wv, Wo) to bf16 in ws.
// ---------------------------------------------------------------------------
__global__ __launch_bounds__(256) void conv_kernel(
    const float* __restrict__ s0, const float* __restrict__ s1,
    const float* __restrict__ s2, const float* __restrict__ s3,
    const float* __restrict__ s4, const float* __restrict__ s5,
    u16* __restrict__ dst)
{
    int e = (blockIdx.x * 256 + threadIdx.x) * 4;
    const float* src; int off;
    if      (e < 4194304) { src = s0; off = e; }
    else if (e < 8388608) { src = s1; off = e - 4194304; }
    else if (e < 8650752) { src = s2; off = e - 8388608; }
    else if (e < 8912896) { src = s3; off = e - 8650752; }
    else if (e < 9175040) { src = s4; off = e - 8912896; }
    else                  { src = s5; off = e - 9175040; }
    f32x4 f = *(const f32x4*)(src + off);
    u16x4 o;
#pragma unroll
    for (int j = 0; j < 4; ++j) o[j] = f2bf(f[j]);
    *(u16x4*)(dst + e) = o;
}

// ---------------------------------------------------------------------------
// Gate precompute, PRE-SWIZZLED into MFMA-fragment order.
// LGx flat index = ((((b*128 + t16)*32 + kt)*64) + lane)*16 + kk*4 + reg
// holds log2(sigmoid(gw*SC+gb)+1e-8) for q = t16*16 + (lane&15),
// k = kt*64 + kk*16 + (lane>>4)*4 + reg.  One wave = one (b,t16,kt) tile.
// ---------------------------------------------------------------------------
__global__ __launch_bounds__(256) void lg_kernel(
    const float* __restrict__ SC, const float* __restrict__ gwp,
    const float* __restrict__ gbp, u16* __restrict__ LGx)
{
    const int flat = blockIdx.x * 256 + threadIdx.x;
    const int lane = flat & 63;
    const int kt   = (flat >> 6) & 31;
    const int t16  = (flat >> 11) & 127;
    const int b    = flat >> 18;
    const int l16 = lane & 15, quad = lane >> 4;
    const float tA = -gwp[0] * L2E, tB = -gbp[0] * L2E;
    const float* row = SC + ((size_t)b * 2048 + t16 * 16 + l16) * 2048
                          + kt * 64 + quad * 4;
    __align__(16) u16 tmp[16];
#pragma unroll
    for (int kk = 0; kk < 4; ++kk) {
        f32x4 x = *(const f32x4*)(row + kk * 16);
#pragma unroll
        for (int reg = 0; reg < 4; ++reg) {
            float g = __builtin_amdgcn_rcpf(
                1.0f + __builtin_amdgcn_exp2f(tA * x[reg] + tB)) + 1e-8f;
            tmp[kk * 4 + reg] = f2bf(__builtin_amdgcn_logf(g));  // log2
        }
    }
    u16* dst = LGx + (size_t)flat * 16;
    *(uint4*)dst       = *(uint4*)tmp;
    *(uint4*)(dst + 8) = *(uint4*)(tmp + 8);
}

// ---------------------------------------------------------------------------
// GEMM core (m97 structure): C[128x128] = A[128x512] * B^T, bf16.
// ---------------------------------------------------------------------------
__device__ __forceinline__ void gemm_core(
    const u16* __restrict__ A, const u16* __restrict__ Bw,
    int m0, int n0, u16* As, u16* Bs, f32x4 acc[4][4])
{
    const int tid = threadIdx.x;
    const int lane = tid & 63, w = tid >> 6;
    const int wm = w >> 1, wn = w & 1;
    const int l16 = lane & 15, quad = lane >> 4;
    const int srow = (lane >> 2), sch = (lane & 3) * 8;
    const f32x4 vzero = {0.f, 0.f, 0.f, 0.f};
#pragma unroll
    for (int i = 0; i < 4; ++i)
#pragma unroll
        for (int j = 0; j < 4; ++j) acc[i][j] = vzero;

    for (int kt = 0; kt < 16; ++kt) {
#pragma unroll
        for (int j = 0; j < 2; ++j) {
            int row = w * 32 + j * 16 + srow;
            gl2lds16(&A[(size_t)(m0 + row) * 512 + kt * 32 + sch],
                     &As[w * 1024 + j * 512]);
            gl2lds16(&Bw[(size_t)(n0 + row) * 512 + kt * 32 + sch],
                     &Bs[w * 1024 + j * 512]);
        }
        __syncthreads();
        s16x8 af[4], bfr[4];
#pragma unroll
        for (int mt = 0; mt < 4; ++mt)
            af[mt] = *(const s16x8*)&As[(wm * 64 + mt * 16 + l16) * 32 + quad * 8];
#pragma unroll
        for (int nt = 0; nt < 4; ++nt)
            bfr[nt] = *(const s16x8*)&Bs[(wn * 64 + nt * 16 + l16) * 32 + quad * 8];
#pragma unroll
        for (int mt = 0; mt < 4; ++mt)
#pragma unroll
            for (int nt = 0; nt < 4; ++nt)
                acc[mt][nt] = __builtin_amdgcn_mfma_f32_16x16x32_bf16(
                    af[mt], bfr[nt], acc[mt][nt], 0, 0, 0);
        __syncthreads();
    }
}

// ---------------------------------------------------------------------------
// QKV projection. job 0=Q (scaled, ->[B,H,N,64]), 1=K, 2=V (-> [B,H,64,N]).
// ---------------------------------------------------------------------------
__global__ __launch_bounds__(256) void proj_kernel(
    const u16* __restrict__ cQin, const u16* __restrict__ cKV,
    const u16* __restrict__ cW,
    const float* __restrict__ bq, const float* __restrict__ bk,
    const float* __restrict__ bv,
    u16* __restrict__ Qh, u16* __restrict__ Kh, u16* __restrict__ Vt)
{
    __shared__ __align__(16) u16 As[128 * 32];
    __shared__ __align__(16) u16 Bs[128 * 32];
    const int job = blockIdx.z;
    const u16* A = (job == 0) ? cQin : cKV;
    const u16* W = cW + (size_t)job * 262144;
    const float* bias = (job == 0) ? bq : (job == 1 ? bk : bv);
    const int m0 = blockIdx.y * 128, n0 = blockIdx.x * 128;
    f32x4 acc[4][4];
    gemm_core(A, W, m0, n0, As, Bs, acc);

    const int tid = threadIdx.x, lane = tid & 63, w = tid >> 6;
    const int wm = w >> 1, wn = w & 1, l16 = lane & 15, quad = lane >> 4;
#pragma unroll
    for (int nt = 0; nt < 4; ++nt) {
        int j = n0 + wn * 64 + nt * 16 + l16;
        float bj = bias[j];
        int h = j >> 6, d = j & 63;
#pragma unroll
        for (int mt = 0; mt < 4; ++mt) {
            int trow = m0 + wm * 64 + mt * 16 + quad * 4;
            int bb = trow >> 11, nn = trow & 2047;
            int bh = bb * 8 + h;
            if (job == 2) {
                u16x4 pv;
#pragma unroll
                for (int reg = 0; reg < 4; ++reg) pv[reg] = f2bf(acc[mt][nt][reg] + bj);
                *(u16x4*)&Vt[(size_t)(bh * 64 + d) * 2048 + nn] = pv;
            } else if (job == 0) {
#pragma unroll
                for (int reg = 0; reg < 4; ++reg)
                    Qh[(size_t)(bh * 2048 + nn + reg) * 64 + d] =
                        f2bf((acc[mt][nt][reg] + bj) * QSCALE);
            } else {
#pragma unroll
                for (int reg = 0; reg < 4; ++reg)
                    Kh[(size_t)(bh * 2048 + nn + reg) * 64 + d] =
                        f2bf(acc[mt][nt][reg] + bj);
            }
        }
    }
}

// ---------------------------------------------------------------------------
// Attention. Block = 512 thr = 8 waves = (1 head, 128 q-rows); wave = 16 q.
// Grid (16 qg, 8 head, 4 b) = 512 blocks = 2 blocks/CU (16 waves/CU) so one
// block's compute overlaps the other's barrier drain. K/V tiles (64x64)
// double-buffered via global_load_lds (waves 0-3 K, 4-7 V; XOR-swizzled).
// Gate read as pre-swizzled LGx: two coalesced b128 loads per iter.
// ---------------------------------------------------------------------------
__global__ __launch_bounds__(512, 4) void attn_kernel(
    const u16* __restrict__ Qh, const u16* __restrict__ Kh,
    const u16* __restrict__ Vt, const u16* __restrict__ LGx,
    u16* __restrict__ Ob)
{
    __shared__ __align__(16) u16 Ks[2][4096];      // [buf][key][d] swizzled
    __shared__ __align__(16) u16 Vs[2][4096];      // [buf][d][key] swizzled
    __shared__ __align__(16) u16 Plds[8][16][68];  // per-wave P
    const int tid = threadIdx.x;
    const int w = tid >> 6, lane = tid & 63;
    const int l16 = lane & 15, quad = lane >> 4;
    const int b = blockIdx.z, head = blockIdx.y, qg = blockIdx.x;
    const int bh = b * 8 + head;
    const int q0 = qg * 128 + w * 16;
    const int t16 = qg * 8 + w;
    const u16* Qp = Qh + (size_t)bh * 131072;
    const u16* Kp = Kh + (size_t)bh * 131072;
    const u16* Vp = Vt + (size_t)bh * 131072;
    const u16* LGt = LGx + ((size_t)((b * 128 + t16) * 32) * 64 + lane) * 16;
    const f32x4 vzero = {0.f, 0.f, 0.f, 0.f};

    // staging: waves 0-3 -> K tile rows, waves 4-7 -> V tile rows (16 each)
    const int sr = lane >> 3;                    // row within 8-row slab
    const int scw = ((lane & 7) ^ sr) * 8;       // XOR-swizzled 8-u16 chunk
    const int slab = (w & 3) * 16;
    const bool isK = (w < 4);
    const u16* sG0 = isK ? (Kp + (size_t)(slab + sr) * 64 + scw)
                         : (Vp + (size_t)(slab + sr) * 2048 + scw);
    const u16* sG1 = isK ? (Kp + (size_t)(slab + 8 + sr) * 64 + scw)
                         : (Vp + (size_t)(slab + 8 + sr) * 2048 + scw);
    const size_t sAdv = isK ? 4096 : 64;         // global advance per k-tile
    u16* sL0 = isK ? &Ks[0][slab * 64] : &Vs[0][slab * 64];
    u16* sL1 = isK ? &Ks[0][(slab + 8) * 64] : &Vs[0][(slab + 8) * 64];

    s16x8 qf[2];  // B-operand: Q[n=q=l16][k=d=kc*32+quad*8+j]
#pragma unroll
    for (int kc = 0; kc < 2; ++kc)
        qf[kc] = *(const s16x8*)&Qp[(size_t)(q0 + l16) * 64 + kc * 32 + quad * 8];
    f32x4 o[4];
    float lsum = 0.f;
#pragma unroll
    for (int dn = 0; dn < 4; ++dn) o[dn] = vzero;

    // prologue: stage k-tile 0 into buffer 0
    gl2lds16(sG0, sL0);
    gl2lds16(sG1, sL1);

    for (int kt = 0; kt < 32; ++kt) {
        __syncthreads();  // tile[cur] ready (drains each wave's staging)
        const int cur = kt & 1;
        if (kt < 31) {
            const int nxt = cur ^ 1;
            gl2lds16(sG0 + (size_t)(kt + 1) * sAdv, sL0 + nxt * 4096);
            gl2lds16(sG1 + (size_t)(kt + 1) * sAdv, sL1 + nxt * 4096);
        }
        const u16* Kb = &Ks[cur][0];
        const u16* Vb = &Vs[cur][0];
        // gate fragment: two coalesced 16B loads
        __align__(16) u16 lgv[16];
        *(uint4*)lgv       = *(const uint4*)(LGt + (size_t)kt * 1024);
        *(uint4*)(lgv + 8) = *(const uint4*)(LGt + (size_t)kt * 1024 + 8);

        // S^T[key][q] = K·Q^T
        f32x4 st[4];
#pragma unroll
        for (int kc = 0; kc < 2; ++kc) {
            s16x8 kf[4];
#pragma unroll
            for (int kk = 0; kk < 4; ++kk)
                kf[kk] = *(const s16x8*)&Kb[(kk * 16 + l16) * 64 +
                                            ((kc * 4 + quad) ^ (l16 & 7)) * 8];
#pragma unroll
            for (int kk = 0; kk < 4; ++kk)
                st[kk] = __builtin_amdgcn_mfma_f32_16x16x32_bf16(
                    kf[kk], qf[kc], kc == 0 ? vzero : st[kk], 0, 0, 0);
        }
        // P = 2^(S*log2e + LG); row sums; stash bf16 P in wave-private LDS
#pragma unroll
        for (int kk = 0; kk < 4; ++kk) {
            u16x4 pp;
#pragma unroll
            for (int reg = 0; reg < 4; ++reg) {
                float p = __builtin_amdgcn_exp2f(st[kk][reg] +
                                                 bf2f(lgv[kk * 4 + reg]));
                lsum += p;
                pp[reg] = f2bf_rn(p);
            }
            *(u16x4*)&Plds[w][l16][kk * 16 + quad * 4] = pp;
        }
        // PV: A = P[m=q][k=key], B = V[n=d][k=key]
#pragma unroll
        for (int kc = 0; kc < 2; ++kc) {
            s16x8 pf = *(const s16x8*)&Plds[w][l16][kc * 32 + quad * 8];
            s16x8 vf[4];
#pragma unroll
            for (int dn = 0; dn < 4; ++dn)
                vf[dn] = *(const s16x8*)&Vb[(dn * 16 + l16) * 64 +
                                            ((kc * 4 + quad) ^ (l16 & 7)) * 8];
#pragma unroll
            for (int dn = 0; dn < 4; ++dn)
                o[dn] = __builtin_amdgcn_mfma_f32_16x16x32_bf16(
                    pf, vf[dn], o[dn], 0, 0, 0);
        }
    }
    // lsum per lane covers q=l16, partial over quads: reduce, redistribute
    lsum += __shfl_xor(lsum, 16, 64);
    lsum += __shfl_xor(lsum, 32, 64);
    float inv = __builtin_amdgcn_rcpf(lsum);
#pragma unroll
    for (int reg = 0; reg < 4; ++reg) {
        float invr = __shfl(inv, quad * 4 + reg, 64);  // lane with l16==q-row
        int trow = b * 2048 + q0 + quad * 4 + reg;
#pragma unroll
        for (int dn = 0; dn < 4; ++dn)
            Ob[(size_t)trow * 512 + head * 64 + dn * 16 + l16] =
                f2bf(o[dn][reg] * invr);
    }
}

// ---------------------------------------------------------------------------
// Output projection: out = Ob @ Wo^T + bo, fp32 out.
// ---------------------------------------------------------------------------
__global__ __launch_bounds__(256) void out_kernel(
    const u16* __restrict__ Ob, const u16* __restrict__ cWo,
    const float* __restrict__ bo, float* __restrict__ out)
{
    __shared__ __align__(16) u16 As[128 * 32];
    __shared__ __align__(16) u16 Bs[128 * 32];
    const int m0 = blockIdx.y * 128, n0 = blockIdx.x * 128;
    f32x4 acc[4][4];
    gemm_core(Ob, cWo, m0, n0, As, Bs, acc);
    const int tid = threadIdx.x, lane = tid & 63, w = tid >> 6;
    const int wm = w >> 1, wn = w & 1, l16 = lane & 15, quad = lane >> 4;
#pragma unroll
    for (int nt = 0; nt < 4; ++nt) {
        int j = n0 + wn * 64 + nt * 16 + l16;
        float bj = bo[j];
#pragma unroll
        for (int mt = 0; mt < 4; ++mt) {
            int t = m0 + wm * 64 + mt * 16 + quad * 4;
#pragma unroll
            for (int reg = 0; reg < 4; ++reg)
                out[(size_t)(t + reg) * 512 + j] = acc[mt][nt][reg] + bj;
        }
    }
}

extern "C" void kernel_launch(void* const* d_in, const int* in_sizes, int n_in,
                              void* d_out, int out_size, void* d_ws, size_t ws_size,
                              hipStream_t stream)
{
    const float* Qin  = (const float*)d_in[0];
    const float* KVin = (const float*)d_in[1];
    const float* SC   = (const float*)d_in[2];
    const float* Wq   = (const float*)d_in[3];
    const float* bq   = (const float*)d_in[4];
    const float* Wk   = (const float*)d_in[5];
    const float* bk   = (const float*)d_in[6];
    const float* Wv   = (const float*)d_in[7];
    const float* bv   = (const float*)d_in[8];
    const float* gw   = (const float*)d_in[9];
    const float* gb   = (const float*)d_in[10];
    const float* Wo   = (const float*)d_in[11];
    const float* bo   = (const float*)d_in[12];
    float* out = (float*)d_out;

    // ws layout (u16 units): conv 9.4M | Qh/Kh/Vt/Ob 4.2M each | LGx 16.8M
    u16* conv = (u16*)d_ws;
    u16* cQin = conv;
    u16* cKV  = conv + 4194304;
    u16* cW   = conv + 8388608;        // Wq,Wk,Wv,Wo each 262,144
    u16* Qh   = conv + 9437184;
    u16* Kh   = Qh + 4194304;
    u16* Vt   = Kh + 4194304;
    u16* Ob   = Vt + 4194304;
    u16* LGx  = Ob + 4194304;          // 16,777,216 u16 = 32 MiB

    hipLaunchKernelGGL(conv_kernel, dim3(9216), dim3(256), 0, stream,
                       Qin, KVin, Wq, Wk, Wv, Wo, conv);
    hipLaunchKernelGGL(lg_kernel, dim3(4096), dim3(256), 0, stream,
                       SC, gw, gb, LGx);
    hipLaunchKernelGGL(proj_kernel, dim3(4, 64, 3), dim3(256), 0, stream,
                       cQin, cKV, cW, bq, bk, bv, Qh, Kh, Vt);
    hipLaunchKernelGGL(attn_kernel, dim3(16, 8, 4), dim3(512), 0, stream,
                       Qh, Kh, Vt, LGx, Ob);
    hipLaunchKernelGGL(out_kernel, dim3(4, 64), dim3(256), 0, stream,
                       Ob, cW + 786432, bo, out);
}

// Round 7
// 244.136 us; speedup vs baseline: 1.5941x; 1.0726x over previous
//
#include <hip/hip_runtime.h>

typedef unsigned short u16;
typedef unsigned int u32;
typedef __attribute__((ext_vector_type(4))) float f32x4;
typedef __attribute__((ext_vector_type(8))) short s16x8;
typedef __attribute__((ext_vector_type(4))) u16 u16x4;

#define L2E 1.4426950408889634f
#define QSCALE 0.18033688011112042f /* (1/8) * log2(e) */

__device__ __forceinline__ float bf2f(u16 u) {
    union { u32 i; float f; } v; v.i = ((u32)u) << 16; return v.f;
}
__device__ __forceinline__ u16 f2bf(float f) {  // RNE
    union { float f; u32 i; } v; v.f = f;
    return (u16)((v.i + 0x7fffu + ((v.i >> 16) & 1u)) >> 16);
}
// pack hi16(a) | hi16(b)<<16  (bf16 truncation, 1-2 ops)
__device__ __forceinline__ u32 pack_hi(float a, float b) {
    union { float f; u32 i; } x, y; x.f = a; y.f = b;
    return (x.i >> 16) | (y.i & 0xFFFF0000u);
}

// async global->LDS, 16B per lane; LDS dest = wave-uniform base + lane*16
__device__ __forceinline__ void gl2lds16(const u16* g, u16* l) {
    __builtin_amdgcn_global_load_lds(
        (const __attribute__((address_space(1))) void*)g,
        (__attribute__((address_space(3))) void*)l, 16, 0, 0);
}

// ---------------------------------------------------------------------------
// prep_kernel = conv (blocks 0..9215) + lg (blocks 9216..13311).
// conv: 6 fp32 tensors (Qin,KVin,Wq,Wk,Wv,Wo) -> bf16 flat region.
// lg:   LGx pre-swizzled gate, flat idx ((((b*128+t16)*32+kt)*64)+lane)*16
//       holds log2(sigmoid(gw*SC+gb)+1e-8) for q=t16*16+(lane&15),
//       k=kt*64+kk*16+(lane>>4)*4+reg.
// ---------------------------------------------------------------------------
__global__ __launch_bounds__(256) void prep_kernel(
    const float* __restrict__ s0, const float* __restrict__ s1,
    const float* __restrict__ s2, const float* __restrict__ s3,
    const float* __restrict__ s4, const float* __restrict__ s5,
    u16* __restrict__ dst,
    const float* __restrict__ SC, const float* __restrict__ gwp,
    const float* __restrict__ gbp, u16* __restrict__ LGx)
{
    if (blockIdx.x < 9216) {
        int e = (blockIdx.x * 256 + threadIdx.x) * 4;
        const float* src; int off;
        if      (e < 4194304) { src = s0; off = e; }
        else if (e < 8388608) { src = s1; off = e - 4194304; }
        else if (e < 8650752) { src = s2; off = e - 8388608; }
        else if (e < 8912896) { src = s3; off = e - 8650752; }
        else if (e < 9175040) { src = s4; off = e - 8912896; }
        else                  { src = s5; off = e - 9175040; }
        f32x4 f = *(const f32x4*)(src + off);
        u16x4 o;
#pragma unroll
        for (int j = 0; j < 4; ++j) o[j] = f2bf(f[j]);
        *(u16x4*)(dst + e) = o;
    } else {
        const int flat = (blockIdx.x - 9216) * 256 + threadIdx.x;
        const int lane = flat & 63;
        const int kt   = (flat >> 6) & 31;
        const int t16  = (flat >> 11) & 127;
        const int b    = flat >> 18;
        const int l16 = lane & 15, quad = lane >> 4;
        const float tA = -gwp[0] * L2E, tB = -gbp[0] * L2E;
        const float* row = SC + ((size_t)b * 2048 + t16 * 16 + l16) * 2048
                              + kt * 64 + quad * 4;
        __align__(16) u16 tmp[16];
#pragma unroll
        for (int kk = 0; kk < 4; ++kk) {
            f32x4 x = *(const f32x4*)(row + kk * 16);
#pragma unroll
            for (int reg = 0; reg < 4; ++reg) {
                float g = __builtin_amdgcn_rcpf(
                    1.0f + __builtin_amdgcn_exp2f(tA * x[reg] + tB)) + 1e-8f;
                tmp[kk * 4 + reg] = f2bf(__builtin_amdgcn_logf(g));  // log2
            }
        }
        u16* d = LGx + (size_t)flat * 16;
        *(uint4*)d       = *(uint4*)tmp;
        *(uint4*)(d + 8) = *(uint4*)(tmp + 8);
    }
}

// ---------------------------------------------------------------------------
// GEMM core, double-buffered: C[128x128] = A[128x512]*B^T, bf16.
// As/Bs are [2][4096] u16. One barrier per K-iter; stage kt+1 into the
// alternate buffer right after the barrier (overlaps MFMA + ds_reads).
// ---------------------------------------------------------------------------
__device__ __forceinline__ void gemm_core(
    const u16* __restrict__ A, const u16* __restrict__ Bw,
    int m0, int n0, u16* As, u16* Bs, f32x4 acc[4][4])
{
    const int tid = threadIdx.x;
    const int lane = tid & 63, w = tid >> 6;
    const int wm = w >> 1, wn = w & 1;
    const int l16 = lane & 15, quad = lane >> 4;
    const int srow = (lane >> 2), sch = (lane & 3) * 8;
    const f32x4 vzero = {0.f, 0.f, 0.f, 0.f};
#pragma unroll
    for (int i = 0; i < 4; ++i)
#pragma unroll
        for (int j = 0; j < 4; ++j) acc[i][j] = vzero;

    // prologue: stage kt=0 into buffer 0
#pragma unroll
    for (int j = 0; j < 2; ++j) {
        int row = w * 32 + j * 16 + srow;
        gl2lds16(&A[(size_t)(m0 + row) * 512 + sch], &As[w * 1024 + j * 512]);
        gl2lds16(&Bw[(size_t)(n0 + row) * 512 + sch], &Bs[w * 1024 + j * 512]);
    }
    for (int kt = 0; kt < 16; ++kt) {
        __syncthreads();  // buf[kt&1] ready (drains each wave's staging)
        const int cur = (kt & 1) * 4096;
        if (kt < 15) {
            const int nxt = ((kt + 1) & 1) * 4096;
#pragma unroll
            for (int j = 0; j < 2; ++j) {
                int row = w * 32 + j * 16 + srow;
                gl2lds16(&A[(size_t)(m0 + row) * 512 + (kt + 1) * 32 + sch],
                         &As[nxt + w * 1024 + j * 512]);
                gl2lds16(&Bw[(size_t)(n0 + row) * 512 + (kt + 1) * 32 + sch],
                         &Bs[nxt + w * 1024 + j * 512]);
            }
        }
        s16x8 af[4], bfr[4];
#pragma unroll
        for (int mt = 0; mt < 4; ++mt)
            af[mt] = *(const s16x8*)&As[cur + (wm * 64 + mt * 16 + l16) * 32 + quad * 8];
#pragma unroll
        for (int nt = 0; nt < 4; ++nt)
            bfr[nt] = *(const s16x8*)&Bs[cur + (wn * 64 + nt * 16 + l16) * 32 + quad * 8];
#pragma unroll
        for (int mt = 0; mt < 4; ++mt)
#pragma unroll
            for (int nt = 0; nt < 4; ++nt)
                acc[mt][nt] = __builtin_amdgcn_mfma_f32_16x16x32_bf16(
                    af[mt], bfr[nt], acc[mt][nt], 0, 0, 0);
    }
}

// ---------------------------------------------------------------------------
// QKV projection. job 0=Q (scaled, ->[B,H,N,64]), 1=K, 2=V (-> [B,H,64,N]).
// ---------------------------------------------------------------------------
__global__ __launch_bounds__(256) void proj_kernel(
    const u16* __restrict__ cQin, const u16* __restrict__ cKV,
    const u16* __restrict__ cW,
    const float* __restrict__ bq, const float* __restrict__ bk,
    const float* __restrict__ bv,
    u16* __restrict__ Qh, u16* __restrict__ Kh, u16* __restrict__ Vt)
{
    __shared__ __align__(16) u16 As[2 * 4096];
    __shared__ __align__(16) u16 Bs[2 * 4096];
    const int job = blockIdx.z;
    const u16* A = (job == 0) ? cQin : cKV;
    const u16* W = cW + (size_t)job * 262144;
    const float* bias = (job == 0) ? bq : (job == 1 ? bk : bv);
    const int m0 = blockIdx.y * 128, n0 = blockIdx.x * 128;
    f32x4 acc[4][4];
    gemm_core(A, W, m0, n0, As, Bs, acc);

    const int tid = threadIdx.x, lane = tid & 63, w = tid >> 6;
    const int wm = w >> 1, wn = w & 1, l16 = lane & 15, quad = lane >> 4;
#pragma unroll
    for (int nt = 0; nt < 4; ++nt) {
        int j = n0 + wn * 64 + nt * 16 + l16;
        float bj = bias[j];
        int h = j >> 6, d = j & 63;
#pragma unroll
        for (int mt = 0; mt < 4; ++mt) {
            int trow = m0 + wm * 64 + mt * 16 + quad * 4;
            int bb = trow >> 11, nn = trow & 2047;
            int bh = bb * 8 + h;
            if (job == 2) {
                u16x4 pv;
#pragma unroll
                for (int reg = 0; reg < 4; ++reg) pv[reg] = f2bf(acc[mt][nt][reg] + bj);
                *(u16x4*)&Vt[(size_t)(bh * 64 + d) * 2048 + nn] = pv;
            } else if (job == 0) {
#pragma unroll
                for (int reg = 0; reg < 4; ++reg)
                    Qh[(size_t)(bh * 2048 + nn + reg) * 64 + d] =
                        f2bf((acc[mt][nt][reg] + bj) * QSCALE);
            } else {
#pragma unroll
                for (int reg = 0; reg < 4; ++reg)
                    Kh[(size_t)(bh * 2048 + nn + reg) * 64 + d] =
                        f2bf(acc[mt][nt][reg] + bj);
            }
        }
    }
}

// ---------------------------------------------------------------------------
// Attention. Block = 512 thr = 8 waves = (1 head, 128 q-rows); wave = 16 q.
// Grid (16,8,4) = 512 blocks = 2/CU. K/V tiles double-buffered via
// global_load_lds. P stored by bf16 TRUNCATION (bias cancels: row-sums are
// computed by MFMA against a ones-fragment from the SAME rounded P, which
// also lands inv exactly where the epilogue needs it — zero shuffles).
// ---------------------------------------------------------------------------
__global__ __launch_bounds__(512, 4) void attn_kernel(
    const u16* __restrict__ Qh, const u16* __restrict__ Kh,
    const u16* __restrict__ Vt, const u16* __restrict__ LGx,
    u16* __restrict__ Ob)
{
    __shared__ __align__(16) u16 Ks[2][4096];      // [buf][key][d] swizzled
    __shared__ __align__(16) u16 Vs[2][4096];      // [buf][d][key] swizzled
    __shared__ __align__(16) u16 Plds[8][16][68];  // per-wave P
    const int tid = threadIdx.x;
    const int w = tid >> 6, lane = tid & 63;
    const int l16 = lane & 15, quad = lane >> 4;
    const int b = blockIdx.z, head = blockIdx.y, qg = blockIdx.x;
    const int bh = b * 8 + head;
    const int q0 = qg * 128 + w * 16;
    const int t16 = qg * 8 + w;
    const u16* Qp = Qh + (size_t)bh * 131072;
    const u16* Kp = Kh + (size_t)bh * 131072;
    const u16* Vp = Vt + (size_t)bh * 131072;
    const u16* LGt = LGx + ((size_t)((b * 128 + t16) * 32) * 64 + lane) * 16;
    const f32x4 vzero = {0.f, 0.f, 0.f, 0.f};
    const s16x8 ones = {0x3F80, 0x3F80, 0x3F80, 0x3F80,
                        0x3F80, 0x3F80, 0x3F80, 0x3F80};  // bf16 1.0 x8

    // staging: waves 0-3 -> K tile rows, waves 4-7 -> V tile rows (16 each)
    const int sr = lane >> 3;
    const int scw = ((lane & 7) ^ sr) * 8;       // XOR-swizzled 8-u16 chunk
    const int slab = (w & 3) * 16;
    const bool isK = (w < 4);
    const u16* sG0 = isK ? (Kp + (size_t)(slab + sr) * 64 + scw)
                         : (Vp + (size_t)(slab + sr) * 2048 + scw);
    const u16* sG1 = isK ? (Kp + (size_t)(slab + 8 + sr) * 64 + scw)
                         : (Vp + (size_t)(slab + 8 + sr) * 2048 + scw);
    const size_t sAdv = isK ? 4096 : 64;
    u16* sL0 = isK ? &Ks[0][slab * 64] : &Vs[0][slab * 64];
    u16* sL1 = isK ? &Ks[0][(slab + 8) * 64] : &Vs[0][(slab + 8) * 64];

    s16x8 qf[2];  // B-operand: Q[n=q=l16][k=d=kc*32+quad*8+j]
#pragma unroll
    for (int kc = 0; kc < 2; ++kc)
        qf[kc] = *(const s16x8*)&Qp[(size_t)(q0 + l16) * 64 + kc * 32 + quad * 8];
    f32x4 o[4], lacc = vzero;
#pragma unroll
    for (int dn = 0; dn < 4; ++dn) o[dn] = vzero;

    gl2lds16(sG0, sL0);
    gl2lds16(sG1, sL1);

    for (int kt = 0; kt < 32; ++kt) {
        __syncthreads();  // tile[cur] ready
        const int cur = kt & 1;
        if (kt < 31) {
            const int nxt = cur ^ 1;
            gl2lds16(sG0 + (size_t)(kt + 1) * sAdv, sL0 + nxt * 4096);
            gl2lds16(sG1 + (size_t)(kt + 1) * sAdv, sL1 + nxt * 4096);
        }
        const u16* Kb = &Ks[cur][0];
        const u16* Vb = &Vs[cur][0];
        __align__(16) u16 lgv[16];
        *(uint4*)lgv       = *(const uint4*)(LGt + (size_t)kt * 1024);
        *(uint4*)(lgv + 8) = *(const uint4*)(LGt + (size_t)kt * 1024 + 8);

        // S^T[key][q] = K·Q^T
        f32x4 st[4];
#pragma unroll
        for (int kc = 0; kc < 2; ++kc) {
            s16x8 kf[4];
#pragma unroll
            for (int kk = 0; kk < 4; ++kk)
                kf[kk] = *(const s16x8*)&Kb[(kk * 16 + l16) * 64 +
                                            ((kc * 4 + quad) ^ (l16 & 7)) * 8];
#pragma unroll
            for (int kk = 0; kk < 4; ++kk)
                st[kk] = __builtin_amdgcn_mfma_f32_16x16x32_bf16(
                    kf[kk], qf[kc], kc == 0 ? vzero : st[kk], 0, 0, 0);
        }
        // P = 2^(S*log2e + LG), truncated to bf16, packed store (1 op/pair)
#pragma unroll
        for (int kk = 0; kk < 4; ++kk) {
            float p0 = __builtin_amdgcn_exp2f(st[kk][0] + bf2f(lgv[kk * 4 + 0]));
            float p1 = __builtin_amdgcn_exp2f(st[kk][1] + bf2f(lgv[kk * 4 + 1]));
            float p2 = __builtin_amdgcn_exp2f(st[kk][2] + bf2f(lgv[kk * 4 + 2]));
            float p3 = __builtin_amdgcn_exp2f(st[kk][3] + bf2f(lgv[kk * 4 + 3]));
            uint2 pk = {pack_hi(p0, p1), pack_hi(p2, p3)};
            *(uint2*)&Plds[w][l16][kk * 16 + quad * 4] = pk;
        }
        // PV + row-sum: A = P[m=q][k=key]; B = V[n=d][k=key] and ones
#pragma unroll
        for (int kc = 0; kc < 2; ++kc) {
            s16x8 pf = *(const s16x8*)&Plds[w][l16][kc * 32 + quad * 8];
            lacc = __builtin_amdgcn_mfma_f32_16x16x32_bf16(pf, ones, lacc, 0, 0, 0);
            s16x8 vf[4];
#pragma unroll
            for (int dn = 0; dn < 4; ++dn)
                vf[dn] = *(const s16x8*)&Vb[(dn * 16 + l16) * 64 +
                                            ((kc * 4 + quad) ^ (l16 & 7)) * 8];
#pragma unroll
            for (int dn = 0; dn < 4; ++dn)
                o[dn] = __builtin_amdgcn_mfma_f32_16x16x32_bf16(
                    pf, vf[dn], o[dn], 0, 0, 0);
        }
    }
    // lacc[reg] = sum_k P[q=quad*4+reg][k] — exactly the row this lane stores
#pragma unroll
    for (int reg = 0; reg < 4; ++reg) {
        float inv = __builtin_amdgcn_rcpf(lacc[reg]);
        int trow = b * 2048 + q0 + quad * 4 + reg;
#pragma unroll
        for (int dn = 0; dn < 4; ++dn)
            Ob[(size_t)trow * 512 + head * 64 + dn * 16 + l16] =
                f2bf(o[dn][reg] * inv);
    }
}

// ---------------------------------------------------------------------------
// Output projection: out = Ob @ Wo^T + bo, fp32 out.
// ---------------------------------------------------------------------------
__global__ __launch_bounds__(256) void out_kernel(
    const u16* __restrict__ Ob, const u16* __restrict__ cWo,
    const float* __restrict__ bo, float* __restrict__ out)
{
    __shared__ __align__(16) u16 As[2 * 4096];
    __shared__ __align__(16) u16 Bs[2 * 4096];
    const int m0 = blockIdx.y * 128, n0 = blockIdx.x * 128;
    f32x4 acc[4][4];
    gemm_core(Ob, cWo, m0, n0, As, Bs, acc);
    const int tid = threadIdx.x, lane = tid & 63, w = tid >> 6;
    const int wm = w >> 1, wn = w & 1, l16 = lane & 15, quad = lane >> 4;
#pragma unroll
    for (int nt = 0; nt < 4; ++nt) {
        int j = n0 + wn * 64 + nt * 16 + l16;
        float bj = bo[j];
#pragma unroll
        for (int mt = 0; mt < 4; ++mt) {
            int t = m0 + wm * 64 + mt * 16 + quad * 4;
#pragma unroll
            for (int reg = 0; reg < 4; ++reg)
                out[(size_t)(t + reg) * 512 + j] = acc[mt][nt][reg] + bj;
        }
    }
}

extern "C" void kernel_launch(void* const* d_in, const int* in_sizes, int n_in,
                              void* d_out, int out_size, void* d_ws, size_t ws_size,
                              hipStream_t stream)
{
    const float* Qin  = (const float*)d_in[0];
    const float* KVin = (const float*)d_in[1];
    const float* SC   = (const float*)d_in[2];
    const float* Wq   = (const float*)d_in[3];
    const float* bq   = (const float*)d_in[4];
    const float* Wk   = (const float*)d_in[5];
    const float* bk   = (const float*)d_in[6];
    const float* Wv   = (const float*)d_in[7];
    const float* bv   = (const float*)d_in[8];
    const float* gw   = (const float*)d_in[9];
    const float* gb   = (const float*)d_in[10];
    const float* Wo   = (const float*)d_in[11];
    const float* bo   = (const float*)d_in[12];
    float* out = (float*)d_out;

    // ws layout (u16 units): conv 9.4M | Qh/Kh/Vt/Ob 4.2M each | LGx 16.8M
    u16* conv = (u16*)d_ws;
    u16* cQin = conv;
    u16* cKV  = conv + 4194304;
    u16* cW   = conv + 8388608;        // Wq,Wk,Wv,Wo each 262,144
    u16* Qh   = conv + 9437184;
    u16* Kh   = Qh + 4194304;
    u16* Vt   = Kh + 4194304;
    u16* Ob   = Vt + 4194304;
    u16* LGx  = Ob + 4194304;          // 16,777,216 u16 = 32 MiB

    hipLaunchKernelGGL(prep_kernel, dim3(13312), dim3(256), 0, stream,
                       Qin, KVin, Wq, Wk, Wv, Wo, conv, SC, gw, gb, LGx);
    hipLaunchKernelGGL(proj_kernel, dim3(4, 64, 3), dim3(256), 0, stream,
                       cQin, cKV, cW, bq, bk, bv, Qh, Kh, Vt);
    hipLaunchKernelGGL(attn_kernel, dim3(16, 8, 4), dim3(512), 0, stream,
                       Qh, Kh, Vt, LGx, Ob);
    hipLaunchKernelGGL(out_kernel, dim3(4, 64), dim3(256), 0, stream,
                       Ob, cW + 786432, bo, out);
}